// Round 9
// baseline (321.428 us; speedup 1.0000x reference)
//
#include <hip/hip_runtime.h>
#include <math.h>

#define B_   8
#define N_   6
#define D_   41
#define C_   64
#define FH_  16
#define FW_  44
#define HW_  (FH_*FW_)          // 704
#define CHW_ ((D_+C_)*FH_*FW_)  // 73920
#define NPIX (B_*N_*FH_*FW_)    // 33792
#define NPT  (NPIX*D_)          // 1385472
#define NXV  200
#define NYV  200
#define NVOX (B_*NXV*NYV)       // 320000
#define NCOL (B_*N_*FW_)        // 2112 columns (b,n,w)
#define FEATBLKS (B_*N_*FH_)    // 768
#define ZEROBLKS 1280
#define NZ4 (NVOX*C_/4)         // float4 count of out = 5,120,000

// exact-rounding helpers: prevent FMA contraction / reassociation
__device__ __forceinline__ float mul_(float a, float b){ return __fmul_rn(a,b); }
__device__ __forceinline__ float add_(float a, float b){ return __fadd_rn(a,b); }
__device__ __forceinline__ float sub_(float a, float b){ return __fsub_rn(a,b); }

// 3x3 inverse mirroring LAPACK getrf (partial pivot) + getrs (divisions kept)
__device__ void inv3(const float* A, float* X){
  float U[3][3];
  float L[3][3] = {{1.f,0.f,0.f},{0.f,1.f,0.f},{0.f,0.f,1.f}};
  int p[3] = {0,1,2};
  #pragma unroll
  for (int i=0;i<3;i++)
    #pragma unroll
    for (int j=0;j<3;j++) U[i][j] = A[i*3+j];
  #pragma unroll
  for (int k=0;k<3;k++){
    int pr = k; float mx = fabsf(U[k][k]);
    #pragma unroll
    for (int r=0;r<3;r++){
      if (r > k){ float v = fabsf(U[r][k]); if (v > mx){ mx = v; pr = r; } }
    }
    if (pr != k){
      #pragma unroll
      for (int j=0;j<3;j++){ float t=U[k][j]; U[k][j]=U[pr][j]; U[pr][j]=t; }
      #pragma unroll
      for (int j=0;j<3;j++){ if (j<k){ float t=L[k][j]; L[k][j]=L[pr][j]; L[pr][j]=t; } }
      int t=p[k]; p[k]=p[pr]; p[pr]=t;
    }
    #pragma unroll
    for (int r=0;r<3;r++){
      if (r > k){
        float m = __fdiv_rn(U[r][k], U[k][k]);
        L[r][k] = m;
        #pragma unroll
        for (int j=0;j<3;j++){ if (j>k) U[r][j] = sub_(U[r][j], mul_(m, U[k][j])); }
      }
    }
  }
  #pragma unroll
  for (int col=0; col<3; col++){
    float y[3];
    #pragma unroll
    for (int i=0;i<3;i++) y[i] = (p[i]==col) ? 1.f : 0.f;
    #pragma unroll
    for (int i=1;i<3;i++)
      #pragma unroll
      for (int j=0;j<3;j++){ if (j<i) y[i] = sub_(y[i], mul_(L[i][j], y[j])); }
    float x[3];
    #pragma unroll
    for (int i=2;i>=0;i--){
      float t = y[i];
      #pragma unroll
      for (int j=0;j<3;j++){ if (j>i) t = sub_(t, mul_(U[i][j], x[j])); }
      x[i] = __fdiv_rn(t, U[i][i]);
    }
    X[0*3+col]=x[0]; X[1*3+col]=x[1]; X[2*3+col]=x[2];
  }
}

// compute the 24 per-(b,n) cam params (identical arithmetic to R1's lss_prep)
__device__ void cam_params(const float* __restrict__ rots, const float* __restrict__ trans,
                           const float* __restrict__ intrins, const float* __restrict__ post_rots,
                           const float* __restrict__ post_trans, int t, float* o){
  float invK[9], invP[9];
  inv3(intrins + t*9, invK);
  inv3(post_rots + t*9, invP);
  const float* R = rots + t*9;
  #pragma unroll
  for (int i=0;i<9;i++) o[i] = invP[i];
  #pragma unroll
  for (int i=0;i<3;i++)
    #pragma unroll
    for (int j=0;j<3;j++){
      float s = mul_(R[i*3+0], invK[0*3+j]);
      s = add_(s, mul_(R[i*3+1], invK[1*3+j]));
      s = add_(s, mul_(R[i*3+2], invK[2*3+j]));
      o[9 + i*3+j] = s;
    }
  o[18]=post_trans[t*3+0]; o[19]=post_trans[t*3+1]; o[20]=post_trans[t*3+2];
  o[21]=trans[t*3+0];      o[22]=trans[t*3+1];      o[23]=trans[t*3+2];
}

// exact same rounding chain as the R1 (passing) kernel; returns gx*NYV+gy or -1
__device__ __forceinline__ int point_vox(const float* __restrict__ cp,
                                         int h, int w, int d){
  float u = mul_((float)w, 703.0f/43.0f);
  float v = mul_((float)h, 17.0f);
  float p0 = sub_(u, cp[18]);
  float p1 = sub_(v, cp[19]);
  float a0 = add_(mul_(cp[0],p0), mul_(cp[1],p1));
  float a1 = add_(mul_(cp[3],p0), mul_(cp[4],p1));
  float a2 = add_(mul_(cp[6],p0), mul_(cp[7],p1));
  float dd = add_(4.0f, (float)d);
  float p2 = sub_(dd, cp[20]);
  float r0 = add_(a0, mul_(cp[2],p2));
  float r1 = add_(a1, mul_(cp[5],p2));
  float r2 = add_(a2, mul_(cp[8],p2));
  float q0 = mul_(r0, r2), q1 = mul_(r1, r2), q2 = r2;
  float g0 = add_(add_(add_(mul_(cp[9], q0), mul_(cp[10],q1)), mul_(cp[11],q2)), cp[21]);
  float g1 = add_(add_(add_(mul_(cp[12],q0), mul_(cp[13],q1)), mul_(cp[14],q2)), cp[22]);
  float g2 = add_(add_(add_(mul_(cp[15],q0), mul_(cp[16],q1)), mul_(cp[17],q2)), cp[23]);
  float bxq = mul_(sub_(g0, -50.0f), 2.0f);
  float byq = mul_(sub_(g1, -50.0f), 2.0f);
  float bzq = __fdiv_rn(sub_(g2, -10.0f), 20.0f);
  int gx=(int)bxq, gy=(int)byq, gz=(int)bzq;
  if ((gx>=0)&(gx<NXV)&(gy>=0)&(gy<NYV)&(gz==0))
    return gx*NYV + gy;
  return -1;
}

// Fused kernel. Blocks [0,FEATBLKS): per-(bn,h) feature transpose + softmax +
// cached geometry. Blocks [FEATBLKS,+ZEROBLKS): float4 zero of OUT.
__global__ __launch_bounds__(256) void lss_featprep(const float* __restrict__ feat,
    const float* __restrict__ rots, const float* __restrict__ trans,
    const float* __restrict__ intrins, const float* __restrict__ post_rots,
    const float* __restrict__ post_trans,
    float* __restrict__ featT, float* __restrict__ dprobA,
    unsigned short* __restrict__ segA, float4* __restrict__ zero_dst){
  int bid = blockIdx.x;
  int tid = threadIdx.x;
  if (bid >= FEATBLKS){
    const float4 z = make_float4(0.f,0.f,0.f,0.f);
    size_t i = (size_t)(bid - FEATBLKS)*256 + tid;
    #pragma unroll
    for (int k=0; k<16; k++){
      if (i < NZ4) zero_dst[i] = z;
      i += (size_t)ZEROBLKS*256;
    }
    return;
  }
  __shared__ float lds[D_+C_][FW_+1];   // 105 x 45
  __shared__ float ssum[FW_];
  __shared__ float cam[24];
  int h = bid & 15, bn = bid >> 4;
  if (tid == 0)
    cam_params(rots, trans, intrins, post_rots, post_trans, bn, cam);
  const float* fb = feat + (size_t)bn*CHW_ + h*FW_;
  for (int i = tid; i < (D_+C_)*FW_; i += 256){
    int ch = i / FW_, w = i - ch*FW_;
    lds[ch][w] = fb[(size_t)ch*HW_ + w];
  }
  __syncthreads();
  if (tid < FW_){
    float m = lds[0][tid];
    for (int d = 1; d < D_; d++) m = fmaxf(m, lds[d][tid]);
    float s = 0.f;
    for (int d = 0; d < D_; d++){ float e = expf(lds[d][tid] - m); lds[d][tid] = e; s += e; }
    ssum[tid] = s;
  }
  __syncthreads();
  int pix0 = bid * FW_;
  for (int i = tid; i < C_*FW_; i += 256){
    int w = i >> 6, c = i & 63;
    featT[(size_t)(pix0 + w)*C_ + c] = lds[D_ + c][w];
  }
  for (int i = tid; i < D_*FW_; i += 256){
    int w = i / D_, d = i - w*D_;
    int pix = pix0 + w;
    dprobA[(size_t)pix*D_ + d] = __fdiv_rn(lds[d][w], ssum[w]);
    int v = point_vox(cam, h, w, d);
    segA[(size_t)pix*D_ + d] = (v < 0) ? 0xFFFFu : (unsigned short)v;
  }
}

// one block per column (b,n,w): LDS-stage seg/dprob/featT, then 4 waves split
// the d-range and run-accumulate; lane = channel. Runs flush DIRECTLY into
// out[b][c][gx][gy] (one 64-lane atomic per run; ~80K runs total).
__global__ __launch_bounds__(256) void lss_cols(const float* __restrict__ featT,
    const unsigned short* __restrict__ segA, const float* __restrict__ dprobA,
    float* __restrict__ out){
  __shared__ unsigned short seg_s[16*D_];
  __shared__ float dp_s [16*D_];
  __shared__ float f_s  [16][C_];
  int col = blockIdx.x;                 // 0..NCOL-1
  int w = col % FW_, bn = col / FW_;
  int b = bn / N_;
  int tid = threadIdx.x, lane = tid & 63, wv = tid >> 6;
  int pixbase = bn*HW_ + w;
  for (int i = tid; i < 16*D_; i += 256){
    int h = i / D_, d = i - h*D_;
    size_t g = (size_t)(pixbase + h*FW_)*D_ + d;
    seg_s[i] = segA[g];
    dp_s[i]  = dprobA[g];
  }
  for (int i = tid; i < 16*C_; i += 256){
    int h = i >> 6, c = i & 63;
    f_s[h][c] = featT[(size_t)(pixbase + h*FW_)*C_ + c];
  }
  __syncthreads();
  size_t base = (size_t)(b*C_ + lane)*(NXV*NYV);
  int d0 = wv*11, d1 = d0 + 11; if (d1 > D_) d1 = D_;
  unsigned curv = 0xFFFFu; float acc = 0.f;
  for (int d = d0; d < d1; d++){
    #pragma unroll
    for (int h = 0; h < 16; h++){
      unsigned v = seg_s[h*D_ + d];
      if (v == 0xFFFFu) continue;
      float p = dp_s[h*D_ + d];
      if (v != curv){
        if (curv != 0xFFFFu)
          atomicAdd(&out[base + curv], acc);
        curv = v; acc = 0.f;
      }
      acc = fmaf(p, f_s[h][lane], acc);
    }
  }
  if (curv != 0xFFFFu)
    atomicAdd(&out[base + curv], acc);
}

// fallback path (ws too small): per-(b,n) cam params to ws, then direct atomics
__global__ void lss_prep(const float* __restrict__ rots, const float* __restrict__ trans,
                         const float* __restrict__ intrins, const float* __restrict__ post_rots,
                         const float* __restrict__ post_trans, float* __restrict__ cam){
  int t = threadIdx.x;
  if (t >= B_*N_) return;
  cam_params(rots, trans, intrins, post_rots, post_trans, t, cam + t*24);
}

__global__ __launch_bounds__(256) void lss_scatter_fb(const float* __restrict__ feat,
    const float* __restrict__ cam, float* __restrict__ pooled){
  int wave = threadIdx.x >> 6, lane = threadIdx.x & 63;
  int pix = blockIdx.x*4 + wave;
  if (pix >= NPIX) return;
  int w = pix % FW_; int t = pix / FW_;
  int h = t % FH_;   int bn = t / FH_;
  int b = bn / N_;
  const float* fb = feat + (size_t)bn*CHW_ + h*FW_ + w;
  float logit = (lane < D_) ? fb[(size_t)lane*HW_] : -INFINITY;
  float mx = logit;
  #pragma unroll
  for (int o=32;o;o>>=1) mx = fmaxf(mx, __shfl_xor(mx,o));
  float e = (lane < D_) ? expf(logit - mx) : 0.f;
  float ssum = e;
  #pragma unroll
  for (int o=32;o;o>>=1) ssum += __shfl_xor(ssum,o);
  float dprob = e / ssum;
  float fc = fb[(size_t)(D_+lane)*HW_];
  for (int d=0; d<D_; d++){
    int v = point_vox(cam + bn*24, h, w, d);
    if (v >= 0){
      float dp = __shfl(dprob, d);
      atomicAdd(&pooled[((size_t)(b*C_ + lane)*NXV*NYV) + v], mul_(dp, fc));
    }
  }
}

extern "C" void kernel_launch(void* const* d_in, const int* in_sizes, int n_in,
                              void* d_out, int out_size, void* d_ws, size_t ws_size,
                              hipStream_t stream) {
  const float* feat       = (const float*)d_in[0];
  const float* rots       = (const float*)d_in[1];
  const float* trans      = (const float*)d_in[2];
  const float* intrins    = (const float*)d_in[3];
  const float* post_rots  = (const float*)d_in[4];
  const float* post_trans = (const float*)d_in[5];
  float* out = (float*)d_out;

  // ws layout: only the pixel/point caches now (~17 MB)
  char* p = (char*)d_ws;
  float*          featT  = (float*)p;          p += (size_t)NPIX*C_*4;  // 8.65 MB
  float*          dprobA = (float*)p;          p += (size_t)NPT*4;      // 5.54 MB
  unsigned short* segA   = (unsigned short*)p; p += (size_t)NPT*2;      // 2.77 MB
  size_t need = (size_t)(p - (char*)d_ws);

  if (ws_size < need){
    hipMemsetAsync(d_out, 0, (size_t)out_size*sizeof(float), stream);
    lss_prep<<<1, 64, 0, stream>>>(rots, trans, intrins, post_rots, post_trans, (float*)d_ws);
    lss_scatter_fb<<<NPIX/4, 256, 0, stream>>>(feat, (float*)d_ws, out);
    return;
  }

  lss_featprep<<<FEATBLKS + ZEROBLKS, 256, 0, stream>>>(
      feat, rots, trans, intrins, post_rots, post_trans,
      featT, dprobA, segA, (float4*)out);
  lss_cols<<<NCOL, 256, 0, stream>>>(featT, segA, dprobA, out);
}

// Round 10
// 84.788 us; speedup vs baseline: 3.7910x; 3.7910x over previous
//
#include <hip/hip_runtime.h>
#include <math.h>

#define B_   8
#define N_   6
#define D_   41
#define C_   64
#define FH_  16
#define FW_  44
#define HW_  (FH_*FW_)          // 704
#define CHW_ ((D_+C_)*FH_*FW_)  // 73920
#define NPIX (B_*N_*FH_*FW_)    // 33792
#define NPT  (NPIX*D_)          // 1385472
#define NXV  200
#define NYV  200
#define NVOX (B_*NXV*NYV)       // 320000
#define NCOL (B_*N_*FW_)        // 2112 columns (b,n,w)
#define FEATBLKS (B_*N_*FH_)    // 768
#define ZEROBLKS 1280
#define NZ4 ((NVOX*C_*4 + NVOX)/16)   // float4 count of pooled+flags = 5,140,000

// exact-rounding helpers: prevent FMA contraction / reassociation
__device__ __forceinline__ float mul_(float a, float b){ return __fmul_rn(a,b); }
__device__ __forceinline__ float add_(float a, float b){ return __fadd_rn(a,b); }
__device__ __forceinline__ float sub_(float a, float b){ return __fsub_rn(a,b); }

// 3x3 inverse mirroring LAPACK getrf (partial pivot) + getrs (divisions kept)
__device__ void inv3(const float* A, float* X){
  float U[3][3];
  float L[3][3] = {{1.f,0.f,0.f},{0.f,1.f,0.f},{0.f,0.f,1.f}};
  int p[3] = {0,1,2};
  #pragma unroll
  for (int i=0;i<3;i++)
    #pragma unroll
    for (int j=0;j<3;j++) U[i][j] = A[i*3+j];
  #pragma unroll
  for (int k=0;k<3;k++){
    int pr = k; float mx = fabsf(U[k][k]);
    #pragma unroll
    for (int r=0;r<3;r++){
      if (r > k){ float v = fabsf(U[r][k]); if (v > mx){ mx = v; pr = r; } }
    }
    if (pr != k){
      #pragma unroll
      for (int j=0;j<3;j++){ float t=U[k][j]; U[k][j]=U[pr][j]; U[pr][j]=t; }
      #pragma unroll
      for (int j=0;j<3;j++){ if (j<k){ float t=L[k][j]; L[k][j]=L[pr][j]; L[pr][j]=t; } }
      int t=p[k]; p[k]=p[pr]; p[pr]=t;
    }
    #pragma unroll
    for (int r=0;r<3;r++){
      if (r > k){
        float m = __fdiv_rn(U[r][k], U[k][k]);
        L[r][k] = m;
        #pragma unroll
        for (int j=0;j<3;j++){ if (j>k) U[r][j] = sub_(U[r][j], mul_(m, U[k][j])); }
      }
    }
  }
  #pragma unroll
  for (int col=0; col<3; col++){
    float y[3];
    #pragma unroll
    for (int i=0;i<3;i++) y[i] = (p[i]==col) ? 1.f : 0.f;
    #pragma unroll
    for (int i=1;i<3;i++)
      #pragma unroll
      for (int j=0;j<3;j++){ if (j<i) y[i] = sub_(y[i], mul_(L[i][j], y[j])); }
    float x[3];
    #pragma unroll
    for (int i=2;i>=0;i--){
      float t = y[i];
      #pragma unroll
      for (int j=0;j<3;j++){ if (j>i) t = sub_(t, mul_(U[i][j], x[j])); }
      x[i] = __fdiv_rn(t, U[i][i]);
    }
    X[0*3+col]=x[0]; X[1*3+col]=x[1]; X[2*3+col]=x[2];
  }
}

// compute the 24 per-(b,n) cam params (identical arithmetic to R1's lss_prep)
__device__ void cam_params(const float* __restrict__ rots, const float* __restrict__ trans,
                           const float* __restrict__ intrins, const float* __restrict__ post_rots,
                           const float* __restrict__ post_trans, int t, float* o){
  float invK[9], invP[9];
  inv3(intrins + t*9, invK);
  inv3(post_rots + t*9, invP);
  const float* R = rots + t*9;
  #pragma unroll
  for (int i=0;i<9;i++) o[i] = invP[i];
  #pragma unroll
  for (int i=0;i<3;i++)
    #pragma unroll
    for (int j=0;j<3;j++){
      float s = mul_(R[i*3+0], invK[0*3+j]);
      s = add_(s, mul_(R[i*3+1], invK[1*3+j]));
      s = add_(s, mul_(R[i*3+2], invK[2*3+j]));
      o[9 + i*3+j] = s;
    }
  o[18]=post_trans[t*3+0]; o[19]=post_trans[t*3+1]; o[20]=post_trans[t*3+2];
  o[21]=trans[t*3+0];      o[22]=trans[t*3+1];      o[23]=trans[t*3+2];
}

// exact same rounding chain as the R1 (passing) kernel; returns gx*NYV+gy or -1
__device__ __forceinline__ int point_vox(const float* __restrict__ cp,
                                         int h, int w, int d){
  float u = mul_((float)w, 703.0f/43.0f);
  float v = mul_((float)h, 17.0f);
  float p0 = sub_(u, cp[18]);
  float p1 = sub_(v, cp[19]);
  float a0 = add_(mul_(cp[0],p0), mul_(cp[1],p1));
  float a1 = add_(mul_(cp[3],p0), mul_(cp[4],p1));
  float a2 = add_(mul_(cp[6],p0), mul_(cp[7],p1));
  float dd = add_(4.0f, (float)d);
  float p2 = sub_(dd, cp[20]);
  float r0 = add_(a0, mul_(cp[2],p2));
  float r1 = add_(a1, mul_(cp[5],p2));
  float r2 = add_(a2, mul_(cp[8],p2));
  float q0 = mul_(r0, r2), q1 = mul_(r1, r2), q2 = r2;
  float g0 = add_(add_(add_(mul_(cp[9], q0), mul_(cp[10],q1)), mul_(cp[11],q2)), cp[21]);
  float g1 = add_(add_(add_(mul_(cp[12],q0), mul_(cp[13],q1)), mul_(cp[14],q2)), cp[22]);
  float g2 = add_(add_(add_(mul_(cp[15],q0), mul_(cp[16],q1)), mul_(cp[17],q2)), cp[23]);
  float bxq = mul_(sub_(g0, -50.0f), 2.0f);
  float byq = mul_(sub_(g1, -50.0f), 2.0f);
  float bzq = __fdiv_rn(sub_(g2, -10.0f), 20.0f);
  int gx=(int)bxq, gy=(int)byq, gz=(int)bzq;
  if ((gx>=0)&(gx<NXV)&(gy>=0)&(gy<NYV)&(gz==0))
    return gx*NYV + gy;
  return -1;
}

// Fused kernel. Blocks [0,FEATBLKS): per-(bn,h) feature transpose + softmax +
// cached geometry. Blocks [FEATBLKS,+ZEROBLKS): float4 zero of pooled+flags.
__global__ __launch_bounds__(256) void lss_featprep(const float* __restrict__ feat,
    const float* __restrict__ rots, const float* __restrict__ trans,
    const float* __restrict__ intrins, const float* __restrict__ post_rots,
    const float* __restrict__ post_trans,
    float* __restrict__ featT, float* __restrict__ dprobA,
    unsigned short* __restrict__ segA, float4* __restrict__ zero_dst){
  int bid = blockIdx.x;
  int tid = threadIdx.x;
  if (bid >= FEATBLKS){
    const float4 z = make_float4(0.f,0.f,0.f,0.f);
    size_t i = (size_t)(bid - FEATBLKS)*256 + tid;
    #pragma unroll
    for (int k=0; k<16; k++){
      if (i < NZ4) zero_dst[i] = z;
      i += (size_t)ZEROBLKS*256;
    }
    return;
  }
  __shared__ float lds[D_+C_][FW_+1];   // 105 x 45
  __shared__ float ssum[FW_];
  __shared__ float cam[24];
  int h = bid & 15, bn = bid >> 4;
  if (tid == 0)
    cam_params(rots, trans, intrins, post_rots, post_trans, bn, cam);
  const float* fb = feat + (size_t)bn*CHW_ + h*FW_;
  for (int i = tid; i < (D_+C_)*FW_; i += 256){
    int ch = i / FW_, w = i - ch*FW_;
    lds[ch][w] = fb[(size_t)ch*HW_ + w];
  }
  __syncthreads();
  if (tid < FW_){
    float m = lds[0][tid];
    for (int d = 1; d < D_; d++) m = fmaxf(m, lds[d][tid]);
    float s = 0.f;
    for (int d = 0; d < D_; d++){ float e = expf(lds[d][tid] - m); lds[d][tid] = e; s += e; }
    ssum[tid] = s;
  }
  __syncthreads();
  int pix0 = bid * FW_;
  for (int i = tid; i < C_*FW_; i += 256){
    int w = i >> 6, c = i & 63;
    featT[(size_t)(pix0 + w)*C_ + c] = lds[D_ + c][w];
  }
  for (int i = tid; i < D_*FW_; i += 256){
    int w = i / D_, d = i - w*D_;
    int pix = pix0 + w;
    dprobA[(size_t)pix*D_ + d] = __fdiv_rn(lds[d][w], ssum[w]);
    int v = point_vox(cam, h, w, d);
    segA[(size_t)pix*D_ + d] = (v < 0) ? 0xFFFFu : (unsigned short)v;
  }
}

// one block per column (b,n,w): LDS-stage seg/dprob/featT, then 4 waves split
// the d-range and run-accumulate; lane = channel. Runs flush into contiguous
// pooled[vox][c] rows (2 cache lines per 64-lane flush) + set flags[vox].
__global__ __launch_bounds__(256) void lss_cols(const float* __restrict__ featT,
    const unsigned short* __restrict__ segA, const float* __restrict__ dprobA,
    float* __restrict__ pooled, unsigned char* __restrict__ flags){
  __shared__ unsigned short seg_s[16*D_];
  __shared__ float dp_s [16*D_];
  __shared__ float f_s  [16][C_];
  int col = blockIdx.x;                 // 0..NCOL-1
  int w = col % FW_, bn = col / FW_;
  int b = bn / N_;
  int tid = threadIdx.x, lane = tid & 63, wv = tid >> 6;
  int pixbase = bn*HW_ + w;
  for (int i = tid; i < 16*D_; i += 256){
    int h = i / D_, d = i - h*D_;
    size_t g = (size_t)(pixbase + h*FW_)*D_ + d;
    seg_s[i] = segA[g];
    dp_s[i]  = dprobA[g];
  }
  for (int i = tid; i < 16*C_; i += 256){
    int h = i >> 6, c = i & 63;
    f_s[h][c] = featT[(size_t)(pixbase + h*FW_)*C_ + c];
  }
  __syncthreads();
  size_t vb = (size_t)b*(NXV*NYV);
  int d0 = wv*11, d1 = d0 + 11; if (d1 > D_) d1 = D_;
  unsigned curv = 0xFFFFu; float acc = 0.f;
  for (int d = d0; d < d1; d++){
    #pragma unroll
    for (int h = 0; h < 16; h++){
      unsigned v = seg_s[h*D_ + d];
      if (v == 0xFFFFu) continue;
      float p = dp_s[h*D_ + d];
      if (v != curv){
        if (curv != 0xFFFFu){
          atomicAdd(&pooled[(vb + curv)*C_ + lane], acc);
          if (lane == 0) flags[vb + curv] = 1;
        }
        curv = v; acc = 0.f;
      }
      acc = fmaf(p, f_s[h][lane], acc);
    }
  }
  if (curv != 0xFFFFu){
    atomicAdd(&pooled[(vb + curv)*C_ + lane], acc);
    if (lane == 0) flags[vb + curv] = 1;
  }
}

// block per (b,x): flags staged to LDS first (no chained loads), then
// predicated float4 full-row reads of pooled into lds[c][y], then fully
// coalesced 800B out-row writes. Unflagged rows become zeros in-register.
__global__ __launch_bounds__(256) void lss_transpose(const float4* __restrict__ pooled4,
    const unsigned char* __restrict__ flags, float* __restrict__ out){
  __shared__ float lds[C_][201];        // 51.5 KB, pad 201 (2-way max)
  __shared__ unsigned char flg[NYV];
  int bid = blockIdx.x;                 // b*200 + x
  int x = bid % NXV, b = bid / NXV;
  int tid = threadIdx.x;
  int vbase = (b*NXV + x)*NYV;
  if (tid < NYV) flg[tid] = flags[vbase + tid];
  __syncthreads();
  const float4 z4 = make_float4(0.f,0.f,0.f,0.f);
  #pragma unroll
  for (int k = 0; k < 13; k++){
    int i = k*256 + tid;                // 3200 float4 reads total
    if (i < NYV*16){
      int y = i >> 4, c4 = i & 15;
      float4 v = flg[y] ? pooled4[(size_t)(vbase + y)*16 + c4] : z4;
      int c = c4*4;
      lds[c+0][y] = v.x; lds[c+1][y] = v.y;
      lds[c+2][y] = v.z; lds[c+3][y] = v.w;
    }
  }
  __syncthreads();
  size_t obase = ((size_t)b*C_*NXV + x)*NYV;
  #pragma unroll
  for (int k = 0; k < 50; k++){
    int i = k*256 + tid;                // 12800 floats, contiguous per c-row
    int c = i / NYV, y = i - c*NYV;
    out[obase + (size_t)c*(NXV*NYV) + y] = lds[c][y];
  }
}

// fallback path (ws too small): per-(b,n) cam params to ws, then direct atomics
__global__ void lss_prep(const float* __restrict__ rots, const float* __restrict__ trans,
                         const float* __restrict__ intrins, const float* __restrict__ post_rots,
                         const float* __restrict__ post_trans, float* __restrict__ cam){
  int t = threadIdx.x;
  if (t >= B_*N_) return;
  cam_params(rots, trans, intrins, post_rots, post_trans, t, cam + t*24);
}

__global__ __launch_bounds__(256) void lss_scatter_fb(const float* __restrict__ feat,
    const float* __restrict__ cam, float* __restrict__ pooled){
  int wave = threadIdx.x >> 6, lane = threadIdx.x & 63;
  int pix = blockIdx.x*4 + wave;
  if (pix >= NPIX) return;
  int w = pix % FW_; int t = pix / FW_;
  int h = t % FH_;   int bn = t / FH_;
  int b = bn / N_;
  const float* fb = feat + (size_t)bn*CHW_ + h*FW_ + w;
  float logit = (lane < D_) ? fb[(size_t)lane*HW_] : -INFINITY;
  float mx = logit;
  #pragma unroll
  for (int o=32;o;o>>=1) mx = fmaxf(mx, __shfl_xor(mx,o));
  float e = (lane < D_) ? expf(logit - mx) : 0.f;
  float ssum = e;
  #pragma unroll
  for (int o=32;o;o>>=1) ssum += __shfl_xor(ssum,o);
  float dprob = e / ssum;
  float fc = fb[(size_t)(D_+lane)*HW_];
  for (int d=0; d<D_; d++){
    int v = point_vox(cam + bn*24, h, w, d);
    if (v >= 0){
      float dp = __shfl(dprob, d);
      atomicAdd(&pooled[((size_t)(b*C_ + lane)*NXV*NYV) + v], mul_(dp, fc));
    }
  }
}

extern "C" void kernel_launch(void* const* d_in, const int* in_sizes, int n_in,
                              void* d_out, int out_size, void* d_ws, size_t ws_size,
                              hipStream_t stream) {
  const float* feat       = (const float*)d_in[0];
  const float* rots       = (const float*)d_in[1];
  const float* trans      = (const float*)d_in[2];
  const float* intrins    = (const float*)d_in[3];
  const float* post_rots  = (const float*)d_in[4];
  const float* post_trans = (const float*)d_in[5];
  float* out = (float*)d_out;

  // ws layout: pooled || flags (zeroed together by fused kernel), then caches
  char* p = (char*)d_ws;
  float*          pooled = (float*)p;          p += (size_t)NVOX*C_*4;  // 81.92 MB
  unsigned char*  flags  = (unsigned char*)p;  p += NVOX;               // 0.32 MB
  float*          featT  = (float*)p;          p += (size_t)NPIX*C_*4;  // 8.65 MB
  float*          dprobA = (float*)p;          p += (size_t)NPT*4;      // 5.54 MB
  unsigned short* segA   = (unsigned short*)p; p += (size_t)NPT*2;      // 2.77 MB
  size_t need = (size_t)(p - (char*)d_ws);

  if (ws_size < need){
    hipMemsetAsync(d_out, 0, (size_t)out_size*sizeof(float), stream);
    lss_prep<<<1, 64, 0, stream>>>(rots, trans, intrins, post_rots, post_trans, (float*)d_ws);
    lss_scatter_fb<<<NPIX/4, 256, 0, stream>>>(feat, (float*)d_ws, out);
    return;
  }

  lss_featprep<<<FEATBLKS + ZEROBLKS, 256, 0, stream>>>(
      feat, rots, trans, intrins, post_rots, post_trans,
      featT, dprobA, segA, (float4*)pooled);
  lss_cols<<<NCOL, 256, 0, stream>>>(featT, segA, dprobA, pooled, flags);
  lss_transpose<<<B_*NXV, 256, 0, stream>>>((const float4*)pooled, flags, out);
}